// Round 17
// baseline (617.732 us; speedup 1.0000x reference)
//
#include <hip/hip_runtime.h>
#include <math.h>

#define BB 64
#define TT 1024
#define DD 32
#define GG 128   // 4*D
#define VOCABN 10000
#define QLEN 100

typedef short short8 __attribute__((ext_vector_type(8)));   // 8 bf16 in 4 VGPRs
typedef float floatx4 __attribute__((ext_vector_type(4)));
typedef unsigned short u16;

__device__ __forceinline__ float fsig(float x) {
    return __builtin_amdgcn_rcpf(1.0f + __expf(-x));
}
__device__ __forceinline__ float readlane_f(float v, int l) {
    return __int_as_float(__builtin_amdgcn_readlane(__float_as_int(v), l));
}
__device__ __forceinline__ u16 f2bf_rne(float x) {
    unsigned u = __float_as_uint(x);
    u += 0x7FFF + ((u >> 16) & 1);
    return (u16)(u >> 16);
}
__device__ __forceinline__ float bf2f(u16 s) {
    return __uint_as_float(((unsigned)s) << 16);
}

// ---------------------------------------------------------------------------
// Kernel 1: LSTM scan v6 — R16 producer/consumer structure (299 µs measured)
// + INLINE bf16 conversion in the consumer (replaces the k_cvt dispatch):
// lanes 0-31 hold h at each step; hh/hl stores are 64B-coalesced, th/tl are
// 2B scattered fire-and-forget — all hide under the scan's ~600 stall
// cyc/step. Queue fused as block 64.
// ---------------------------------------------------------------------------
#define UU 8
__global__
__attribute__((amdgpu_flat_work_group_size(128, 128)))
__attribute__((amdgpu_waves_per_eu(1, 1)))
void k_lstm_scan(const int* __restrict__ ids,
                 const float* __restrict__ emb,
                 const float* __restrict__ klstm,
                 const float* __restrict__ bias,
                 const float* __restrict__ rk,
                 float* __restrict__ hout,
                 u16* __restrict__ hh, u16* __restrict__ hl,
                 u16* __restrict__ th, u16* __restrict__ tl,
                 int* __restrict__ list,
                 float* __restrict__ outq) {
    const int b = blockIdx.x;
    const int tid = threadIdx.x;
    const int wv = tid >> 6;   // wave 0 consumer / wave 1 producer
    const int l = tid & 63;
    if (b >= BB) {
        if (wv != 0) return;
        // ---- fused zero-index queue (single wave, no barriers) ----
        const int4* v4 = (const int4*)ids;
        const int C4 = (BB * TT) / 4 / 64;
        const int b4 = l * C4;
        int cnt = 0;
#pragma unroll 4
        for (int i = 0; i < C4; ++i) {
            int4 v = v4[b4 + i];
            cnt += (v.x == 0 || (unsigned)v.x >= VOCABN);
            cnt += (v.y == 0 || (unsigned)v.y >= VOCABN);
            cnt += (v.z == 0 || (unsigned)v.z >= VOCABN);
            cnt += (v.w == 0 || (unsigned)v.w >= VOCABN);
        }
        int scan = cnt;
#pragma unroll
        for (int o = 1; o < 64; o <<= 1) {
            int nn = __shfl_up(scan, o);
            if (l >= o) scan += nn;
        }
        const int total = __shfl(scan, 63);
        int off = scan - cnt;
        const int base = l * (C4 * 4);
#pragma unroll 4
        for (int i = 0; i < C4; ++i) {
            int4 v = v4[b4 + i];
            if (v.x == 0 || (unsigned)v.x >= VOCABN) list[off++] = base + 4 * i;
            if (v.y == 0 || (unsigned)v.y >= VOCABN) list[off++] = base + 4 * i + 1;
            if (v.z == 0 || (unsigned)v.z >= VOCABN) list[off++] = base + 4 * i + 2;
            if (v.w == 0 || (unsigned)v.w >= VOCABN) list[off++] = base + 4 * i + 3;
        }
        __threadfence();
        const int Kc = total < QLEN ? total : QLEN;
        for (int t = l; t < QLEN; t += 64) {
            float ii = -1.0f, jj = -1.0f;
            if (t >= QLEN - Kc) {
                int pos = list[total - QLEN + t];
                ii = (float)(pos >> 10);
                jj = (float)(pos & (TT - 1));
            }
            outq[2 * t] = ii;
            outq[2 * t + 1] = jj;
        }
        return;
    }

    __shared__ float ring[2][UU][GG];   // 8 KB double-buffered xg ring
    const int* idsb = ids + b * TT;

    if (wv == 1) {
        // ---------------- producer: xg tokens 8 ahead ----------------
        const int ja = l, jb = l + 64;
        float ka[DD], kb[DD];
#pragma unroll
        for (int d = 0; d < DD; ++d) {
            ka[d] = klstm[d * GG + ja];
            kb[d] = klstm[d * GG + jb];
        }
        const float bja = bias[ja], bjb = bias[jb];
        const int dd = l & 31;

#define PROD_TOKEN(TOK, SEL, U, EV)                                          \
        {                                                                    \
            float za0 = bja, zb0 = bjb;                                      \
            float za1 = 0.f, za2 = 0.f, za3 = 0.f;                           \
            float zb1 = 0.f, zb2 = 0.f, zb3 = 0.f;                           \
            _Pragma("unroll")                                                \
            for (int k = 0; k < DD; k += 4) {                                \
                float e0 = readlane_f(EV, k);                                \
                float e1 = readlane_f(EV, k + 1);                            \
                float e2 = readlane_f(EV, k + 2);                            \
                float e3 = readlane_f(EV, k + 3);                            \
                za0 = fmaf(e0, ka[k], za0);     zb0 = fmaf(e0, kb[k], zb0);  \
                za1 = fmaf(e1, ka[k + 1], za1); zb1 = fmaf(e1, kb[k + 1], zb1); \
                za2 = fmaf(e2, ka[k + 2], za2); zb2 = fmaf(e2, kb[k + 2], zb2); \
                za3 = fmaf(e3, ka[k + 3], za3); zb3 = fmaf(e3, kb[k + 3], zb3); \
            }                                                                \
            ring[SEL][U][ja] = (za0 + za1) + (za2 + za3);                    \
            ring[SEL][U][jb] = (zb0 + zb1) + (zb2 + zb3);                    \
        }

        {
            int id0 = idsb[0]; if ((unsigned)id0 >= VOCABN) id0 = 0;
            float ec = emb[id0 * DD + dd];
#pragma unroll
            for (int u = 0; u < UU; ++u) {
                float en = 0.f;
                if (u + 1 < UU) {
                    int idn = idsb[u + 1]; if ((unsigned)idn >= VOCABN) idn = 0;
                    en = emb[idn * DD + dd];
                }
                PROD_TOKEN(u, 0, u, ec)
                ec = en;
            }
        }
        __syncthreads();
        int sel = 0;
        for (int t0 = 0; t0 < TT; t0 += UU) {
            if (t0 + UU < TT) {
                const int s = sel ^ 1;
                int id0 = idsb[t0 + UU]; if ((unsigned)id0 >= VOCABN) id0 = 0;
                float ec = emb[id0 * DD + dd];
#pragma unroll
                for (int u = 0; u < UU; ++u) {
                    float en = 0.f;
                    if (u + 1 < UU) {
                        int tn = t0 + UU + u + 1;
                        if (tn > TT - 1) tn = TT - 1;
                        int idn = idsb[tn]; if ((unsigned)idn >= VOCABN) idn = 0;
                        en = emb[idn * DD + dd];
                    }
                    PROD_TOKEN(t0 + UU + u, s, u, ec)
                    ec = en;
                }
            }
            __syncthreads();
            sel ^= 1;
        }
#undef PROD_TOKEN
        return;
    }

    // ---------------- consumer: R3-exact scan + inline bf16 stores ----------
    const int d = l & 31;
    const bool hi = l >= 32;
    const int ga = (hi ? 32 : 0) + d;
    const int gb = (hi ? 96 : 64) + d;
    float rka[DD], rkb[DD];
#pragma unroll
    for (int k = 0; k < DD; ++k) { rka[k] = rk[k * GG + ga]; rkb[k] = rk[k * GG + gb]; }
    float* hb = hout + (size_t)b * TT * DD;
    u16* HHb = hh + (size_t)b * TT * DD;
    u16* HLb = hl + (size_t)b * TT * DD;
    u16* THb = th + (size_t)b * DD * TT;
    u16* TLb = tl + (size_t)b * DD * TT;

    float h = 0.0f, c = 0.0f;
    __syncthreads();   // matches producer prologue barrier
    int sel = 0;
    for (int t0 = 0; t0 < TT; t0 += UU) {
        float pa[UU], pb[UU];
#pragma unroll
        for (int u = 0; u < UU; ++u) {
            pa[u] = ring[sel][u][ga];
            pb[u] = ring[sel][u][gb];
        }
#pragma unroll
        for (int u = 0; u < UU; ++u) {
            float za0 = pa[u], zb0 = pb[u];
            float za1 = 0.f, za2 = 0.f, za3 = 0.f;
            float zb1 = 0.f, zb2 = 0.f, zb3 = 0.f;
#pragma unroll
            for (int k = 0; k < DD; k += 4) {
                float h0 = readlane_f(h, k);
                float h1 = readlane_f(h, k + 1);
                float h2 = readlane_f(h, k + 2);
                float h3 = readlane_f(h, k + 3);
                za0 = fmaf(h0, rka[k], za0);     zb0 = fmaf(h0, rkb[k], zb0);
                za1 = fmaf(h1, rka[k + 1], za1); zb1 = fmaf(h1, rkb[k + 1], zb1);
                za2 = fmaf(h2, rka[k + 2], za2); zb2 = fmaf(h2, rkb[k + 2], zb2);
                za3 = fmaf(h3, rka[k + 3], za3); zb3 = fmaf(h3, rkb[k + 3], zb3);
            }
            float za = (za0 + za1) + (za2 + za3);
            float zb = (zb0 + zb1) + (zb2 + zb3);
            float a = fsig(za);                       // sig(i) lo / sig(f) hi
            float zbm = hi ? zb : 2.0f * zb;
            float s2 = fsig(zbm);
            float bv = hi ? s2 : 2.0f * s2 - 1.0f;    // sig(o) hi / tanh(g) lo
            float fg = __shfl_xor(a, 32);
            float og = __shfl_xor(bv, 32);
            c = fmaf(fg, c, a * bv);
            float tc = 2.0f * fsig(2.0f * c) - 1.0f;
            h = og * tc;
            if (!hi) {
                const int t = t0 + u;
                hb[t * DD + d] = h;
                u16 hv16 = f2bf_rne(h);
                u16 lv16 = f2bf_rne(h - bf2f(hv16));
                HHb[t * DD + d] = hv16;      // 64B coalesced
                HLb[t * DD + d] = lv16;
                THb[d * TT + t] = hv16;      // scattered, fire-and-forget
                TLb[d * TT + t] = lv16;
            }
        }
        __syncthreads();
        sel ^= 1;
    }
}

// ---------------------------------------------------------------------------
// Kernel 2: attention on MFMA (R16 P-lag version, absmax 0.0 verified) +
// FUSED ymlp epilogue: each block threadfences + atomicAdds its batch
// counter; the 16th (last) block of the batch runs the ymlp body for that
// batch. Device-scope fence/atomic -> correct regardless of XCD placement;
// deadlock-free (no spinning). LDS phase-aliased: attn P-buf (10.2 KB) and
// ymlp tiles (16.4 KB) share one 16.7 KB arena -> 4 blocks/CU preserved.
// ---------------------------------------------------------------------------
__global__ __launch_bounds__(256, 4) void k_attn(const u16* __restrict__ hh,
                                                 const u16* __restrict__ hl,
                                                 const u16* __restrict__ th,
                                                 const u16* __restrict__ tl,
                                                 const float* __restrict__ hf,
                                                 const float* __restrict__ W1,
                                                 const float* __restrict__ b1,
                                                 const float* __restrict__ W2,
                                                 const float* __restrict__ b2,
                                                 float* __restrict__ ctx,
                                                 int* __restrict__ counters,
                                                 float* __restrict__ out) {
    __shared__ __align__(16) char smem[16896];
    __shared__ int amLast;
    u16* plds = (u16*)smem;   // [4][2][16*40] u16 = 10240 B (attn phase)
    const int tid = threadIdx.x;
    const int w = tid >> 6;
    const int l = tid & 63;
    const int m = l & 15;
    const int g = l >> 4;
    const int b = blockIdx.x & 63;              // XCD swizzle: XCD = b % 8
    const int qt = (blockIdx.x >> 6) * 4 + w;
    const int q0 = qt * 16;
    const size_t rb = (size_t)b * TT * DD;
    const size_t tb = (size_t)b * DD * TT;

    const short8 Qh = *(const short8*)&hh[rb + (size_t)(q0 + m) * DD + g * 8];
    const short8 Ql = *(const short8*)&hl[rb + (size_t)(q0 + m) * DD + g * 8];
    short8 ONES;
#pragma unroll
    for (int j = 0; j < 8; ++j) ONES[j] = (short)0x3F80;

    floatx4 c0 = {0.f, 0.f, 0.f, 0.f};
    floatx4 c1 = {0.f, 0.f, 0.f, 0.f};
    floatx4 la = {0.f, 0.f, 0.f, 0.f};

#define S_BLOCK(KH_A, KL_A, KH_B, KL_B, SA, SB)                               \
    SA = __builtin_amdgcn_mfma_f32_16x16x32_bf16(Qh, KH_A, SA, 0, 0, 0);      \
    SA = __builtin_amdgcn_mfma_f32_16x16x32_bf16(Qh, KL_A, SA, 0, 0, 0);      \
    SA = __builtin_amdgcn_mfma_f32_16x16x32_bf16(Ql, KH_A, SA, 0, 0, 0);      \
    SB = __builtin_amdgcn_mfma_f32_16x16x32_bf16(Qh, KH_B, SB, 0, 0, 0);      \
    SB = __builtin_amdgcn_mfma_f32_16x16x32_bf16(Qh, KL_B, SB, 0, 0, 0);      \
    SB = __builtin_amdgcn_mfma_f32_16x16x32_bf16(Ql, KH_B, SB, 0, 0, 0);

    // ---- kp = 0: S + exp + write slot0; no PV yet ----
    {
        short8 KhA = *(const short8*)&hh[rb + (size_t)(m) * DD + g * 8];
        short8 KlA = *(const short8*)&hl[rb + (size_t)(m) * DD + g * 8];
        short8 KhB = *(const short8*)&hh[rb + (size_t)(16 + m) * DD + g * 8];
        short8 KlB = *(const short8*)&hl[rb + (size_t)(16 + m) * DD + g * 8];
        floatx4 sA = {0.f, 0.f, 0.f, 0.f};
        floatx4 sB = {0.f, 0.f, 0.f, 0.f};
        S_BLOCK(KhA, KlA, KhB, KlB, sA, sB)
        u16* lds0 = plds + w * 1280;
#pragma unroll
        for (int r = 0; r < 4; ++r) {
            lds0[(g * 4 + r) * 40 + m]      = f2bf_rne(__expf(sA[r]));
            lds0[(g * 4 + r) * 40 + 16 + m] = f2bf_rne(__expf(sB[r]));
        }
    }
    short8 Vh0 = *(const short8*)&th[tb + (size_t)m * TT + g * 8];
    short8 Vl0 = *(const short8*)&tl[tb + (size_t)m * TT + g * 8];
    short8 Vh1 = *(const short8*)&th[tb + (size_t)(16 + m) * TT + g * 8];
    short8 Vl1 = *(const short8*)&tl[tb + (size_t)(16 + m) * TT + g * 8];
    short8 KhA = *(const short8*)&hh[rb + (size_t)(32 + m) * DD + g * 8];
    short8 KlA = *(const short8*)&hl[rb + (size_t)(32 + m) * DD + g * 8];
    short8 KhB = *(const short8*)&hh[rb + (size_t)(48 + m) * DD + g * 8];
    short8 KlB = *(const short8*)&hl[rb + (size_t)(48 + m) * DD + g * 8];

#pragma unroll 1
    for (int kp = 1; kp < 32; ++kp) {
        const int knK = (kp < 31) ? (kp + 1) * 32 : 0;
        const int knV = kp * 32;
        short8 nKhA = *(const short8*)&hh[rb + (size_t)(knK + m) * DD + g * 8];
        short8 nKlA = *(const short8*)&hl[rb + (size_t)(knK + m) * DD + g * 8];
        short8 nKhB = *(const short8*)&hh[rb + (size_t)(knK + 16 + m) * DD + g * 8];
        short8 nKlB = *(const short8*)&hl[rb + (size_t)(knK + 16 + m) * DD + g * 8];
        short8 nVh0 = *(const short8*)&th[tb + (size_t)m * TT + knV + g * 8];
        short8 nVl0 = *(const short8*)&tl[tb + (size_t)m * TT + knV + g * 8];
        short8 nVh1 = *(const short8*)&th[tb + (size_t)(16 + m) * TT + knV + g * 8];
        short8 nVl1 = *(const short8*)&tl[tb + (size_t)(16 + m) * TT + knV + g * 8];

        floatx4 sA = {0.f, 0.f, 0.f, 0.f};
        floatx4 sB = {0.f, 0.f, 0.f, 0.f};
        S_BLOCK(KhA, KlA, KhB, KlB, sA, sB)

        const short8 P = *(const short8*)&plds[w * 1280 + ((kp - 1) & 1) * 640 + m * 40 + g * 8];

        u16 pe[8];
#pragma unroll
        for (int r = 0; r < 4; ++r) {
            pe[r]     = f2bf_rne(__expf(sA[r]));
            pe[4 + r] = f2bf_rne(__expf(sB[r]));
        }

        c0 = __builtin_amdgcn_mfma_f32_16x16x32_bf16(P, Vh0, c0, 0, 0, 0);
        c0 = __builtin_amdgcn_mfma_f32_16x16x32_bf16(P, Vl0, c0, 0, 0, 0);
        c1 = __builtin_amdgcn_mfma_f32_16x16x32_bf16(P, Vh1, c1, 0, 0, 0);
        c1 = __builtin_amdgcn_mfma_f32_16x16x32_bf16(P, Vl1, c1, 0, 0, 0);
        la = __builtin_amdgcn_mfma_f32_16x16x32_bf16(P, ONES, la, 0, 0, 0);

        u16* lds = plds + w * 1280 + (kp & 1) * 640;
#pragma unroll
        for (int r = 0; r < 4; ++r) {
            lds[(g * 4 + r) * 40 + m]      = pe[r];
            lds[(g * 4 + r) * 40 + 16 + m] = pe[4 + r];
        }

        KhA = nKhA; KlA = nKlA; KhB = nKhB; KlB = nKlB;
        Vh0 = nVh0; Vl0 = nVl0; Vh1 = nVh1; Vl1 = nVl1;
    }
    {
        const short8 P = *(const short8*)&plds[w * 1280 + (31 & 1) * 640 + m * 40 + g * 8];
        c0 = __builtin_amdgcn_mfma_f32_16x16x32_bf16(P, Vh0, c0, 0, 0, 0);
        c0 = __builtin_amdgcn_mfma_f32_16x16x32_bf16(P, Vl0, c0, 0, 0, 0);
        c1 = __builtin_amdgcn_mfma_f32_16x16x32_bf16(P, Vh1, c1, 0, 0, 0);
        c1 = __builtin_amdgcn_mfma_f32_16x16x32_bf16(P, Vl1, c1, 0, 0, 0);
        la = __builtin_amdgcn_mfma_f32_16x16x32_bf16(P, ONES, la, 0, 0, 0);
    }
#undef S_BLOCK
#pragma unroll
    for (int r = 0; r < 4; ++r) {
        float linv = __builtin_amdgcn_rcpf(la[r]);
        float* crow = ctx + rb + (size_t)(q0 + g * 4 + r) * DD;
        crow[m]      = c0[r] * linv;
        crow[16 + m] = c1[r] * linv;
    }

    // ---- fused ymlp epilogue: last block of this batch does the MLP ----
    __threadfence();
    if (tid == 0) {
        int prev = atomicAdd(&counters[b], 1);
        amLast = (prev == 15);
    }
    __syncthreads();
    if (!amLast) return;

    float* cs = (float*)smem;            // 8 KB (64x32)
    float* hs = (float*)(smem + 8192);   // 8 KB
    const float* cb = ctx + rb;
    const float* hb = hf + rb;
    const int e = tid & 31;
    const int d4 = (tid >> 5) * 4;
    float acc[4] = {0.f, 0.f, 0.f, 0.f};
    __syncthreads();
    for (int kt = 0; kt < 16; ++kt) {
        const float4* s1 = (const float4*)(cb + (size_t)kt * 64 * DD);
        const float4* s2 = (const float4*)(hb + (size_t)kt * 64 * DD);
        ((float4*)cs)[tid]       = s1[tid];
        ((float4*)cs)[tid + 256] = s1[tid + 256];
        ((float4*)hs)[tid]       = s2[tid];
        ((float4*)hs)[tid + 256] = s2[tid + 256];
        __syncthreads();
#pragma unroll 2
        for (int s = 0; s < 64; ++s) {
            float hv = hs[s * DD + e];
            float4 cv = *(const float4*)&cs[s * DD + d4];
            acc[0] = fmaf(cv.x, hv, acc[0]);
            acc[1] = fmaf(cv.y, hv, acc[1]);
            acc[2] = fmaf(cv.z, hv, acc[2]);
            acc[3] = fmaf(cv.w, hv, acc[3]);
        }
        __syncthreads();
    }
    float* ys = (float*)smem;            // 4 KB (32x32), overlays dead cs
    float* yr = (float*)(smem + 4096);   // 4.2 KB (32x33), overlays dead hs
#pragma unroll
    for (int r = 0; r < 4; ++r) ys[(d4 + r) * DD + e] = acc[r];
    __syncthreads();
#pragma unroll
    for (int r = 0; r < 4; ++r) {
        float v = b1[e];
#pragma unroll
        for (int ee = 0; ee < DD; ++ee) v += ys[(d4 + r) * DD + ee] * W1[ee * DD + e];
        yr[(d4 + r) * 33 + e] = fmaxf(v, 0.0f);
    }
    __syncthreads();
    if (tid < DD) {
        float v = b2[0];
#pragma unroll
        for (int ee = 0; ee < DD; ++ee) v += yr[tid * 33 + ee] * W2[ee];
        out[b * DD + tid] = 1.0f / (1.0f + expf(-v));
    }
}

// ---------------------------------------------------------------------------
extern "C" void kernel_launch(void* const* d_in, const int* in_sizes, int n_in,
                              void* d_out, int out_size, void* d_ws, size_t ws_size,
                              hipStream_t stream) {
    const int* ids   = (const int*)d_in[0];
    const float* emb = (const float*)d_in[1];
    const float* kl  = (const float*)d_in[2];
    const float* rk  = (const float*)d_in[3];
    const float* bl  = (const float*)d_in[4];
    const float* W1  = (const float*)d_in[5];
    const float* b1  = (const float*)d_in[6];
    const float* W2  = (const float*)d_in[7];
    const float* b2  = (const float*)d_in[8];
    float* out = (float*)d_out;

    char* ws = (char*)d_ws;
    const size_t H_ELEMS = (size_t)BB * TT * DD;   // 2,097,152
    u16* hh    = (u16*)ws;                          // 4 MB
    u16* hl    = (u16*)(ws + H_ELEMS * 2);          // 4 MB
    u16* th    = (u16*)(ws + H_ELEMS * 4);          // 4 MB
    u16* tl    = (u16*)(ws + H_ELEMS * 6);          // 4 MB
    float* h   = (float*)(ws + H_ELEMS * 8);        // 8 MB
    float* ctx = (float*)(ws + H_ELEMS * 12);       // 8 MB
    int* list  = (int*)(ws + H_ELEMS * 16);         // 256 KB
    int* cnts  = (int*)(ws + H_ELEMS * 16 + 262144);// 256 B

    hipMemsetAsync(cnts, 0, BB * sizeof(int), stream);
    k_lstm_scan<<<BB + 1, 128, 0, stream>>>(ids, emb, kl, bl, rk, h,
                                            hh, hl, th, tl, list, out + BB * DD);
    k_attn<<<BB * 16, 256, 0, stream>>>(hh, hl, th, tl, h,
                                        W1, b1, W2, b2, ctx, cnts, out);
}

// Round 18
// 497.540 us; speedup vs baseline: 1.2416x; 1.2416x over previous
//
#include <hip/hip_runtime.h>
#include <math.h>

#define BB 64
#define TT 1024
#define DD 32
#define GG 128   // 4*D
#define VOCABN 10000
#define QLEN 100

typedef short short8 __attribute__((ext_vector_type(8)));   // 8 bf16 in 4 VGPRs
typedef float floatx4 __attribute__((ext_vector_type(4)));
typedef unsigned short u16;

__device__ __forceinline__ float fsig(float x) {
    return __builtin_amdgcn_rcpf(1.0f + __expf(-x));
}
__device__ __forceinline__ float readlane_f(float v, int l) {
    return __int_as_float(__builtin_amdgcn_readlane(__float_as_int(v), l));
}
__device__ __forceinline__ u16 f2bf_rne(float x) {
    unsigned u = __float_as_uint(x);
    u += 0x7FFF + ((u >> 16) & 1);
    return (u16)(u >> 16);
}
__device__ __forceinline__ float bf2f(u16 s) {
    return __uint_as_float(((unsigned)s) << 16);
}

// ---------------------------------------------------------------------------
// Kernel 1: LSTM scan — R16 EXACT (measured 299 µs). wave0 = R3 consumer,
// wave1 = xg producer into a double-buffered LDS ring. Queue fused as blk 64.
// R17 lessons (reverted): inline bf16 cvt in the consumer (+39 µs — extra
// ops sit in the latency chain's issue stream, NOT free under stalls);
// attn+ymlp mega-kernel (register pressure/spill, +80 µs).
// ---------------------------------------------------------------------------
#define UU 8
__global__
__attribute__((amdgpu_flat_work_group_size(128, 128)))
__attribute__((amdgpu_waves_per_eu(1, 1)))
void k_lstm_scan(const int* __restrict__ ids,
                 const float* __restrict__ emb,
                 const float* __restrict__ klstm,
                 const float* __restrict__ bias,
                 const float* __restrict__ rk,
                 float* __restrict__ hout,
                 int* __restrict__ list,
                 float* __restrict__ outq) {
    const int b = blockIdx.x;
    const int tid = threadIdx.x;
    const int wv = tid >> 6;   // wave 0 consumer / wave 1 producer
    const int l = tid & 63;
    if (b >= BB) {
        if (wv != 0) return;
        // ---- fused zero-index queue (single wave, no barriers) ----
        const int4* v4 = (const int4*)ids;
        const int C4 = (BB * TT) / 4 / 64;
        const int b4 = l * C4;
        int cnt = 0;
#pragma unroll 4
        for (int i = 0; i < C4; ++i) {
            int4 v = v4[b4 + i];
            cnt += (v.x == 0 || (unsigned)v.x >= VOCABN);
            cnt += (v.y == 0 || (unsigned)v.y >= VOCABN);
            cnt += (v.z == 0 || (unsigned)v.z >= VOCABN);
            cnt += (v.w == 0 || (unsigned)v.w >= VOCABN);
        }
        int scan = cnt;
#pragma unroll
        for (int o = 1; o < 64; o <<= 1) {
            int nn = __shfl_up(scan, o);
            if (l >= o) scan += nn;
        }
        const int total = __shfl(scan, 63);
        int off = scan - cnt;
        const int base = l * (C4 * 4);
#pragma unroll 4
        for (int i = 0; i < C4; ++i) {
            int4 v = v4[b4 + i];
            if (v.x == 0 || (unsigned)v.x >= VOCABN) list[off++] = base + 4 * i;
            if (v.y == 0 || (unsigned)v.y >= VOCABN) list[off++] = base + 4 * i + 1;
            if (v.z == 0 || (unsigned)v.z >= VOCABN) list[off++] = base + 4 * i + 2;
            if (v.w == 0 || (unsigned)v.w >= VOCABN) list[off++] = base + 4 * i + 3;
        }
        __threadfence();
        const int Kc = total < QLEN ? total : QLEN;
        for (int t = l; t < QLEN; t += 64) {
            float ii = -1.0f, jj = -1.0f;
            if (t >= QLEN - Kc) {
                int pos = list[total - QLEN + t];
                ii = (float)(pos >> 10);
                jj = (float)(pos & (TT - 1));
            }
            outq[2 * t] = ii;
            outq[2 * t + 1] = jj;
        }
        return;
    }

    __shared__ float ring[2][UU][GG];   // 8 KB double-buffered xg ring
    const int* idsb = ids + b * TT;

    if (wv == 1) {
        // ---------------- producer: xg tokens 8 ahead ----------------
        const int ja = l, jb = l + 64;
        float ka[DD], kb[DD];
#pragma unroll
        for (int d = 0; d < DD; ++d) {
            ka[d] = klstm[d * GG + ja];
            kb[d] = klstm[d * GG + jb];
        }
        const float bja = bias[ja], bjb = bias[jb];
        const int dd = l & 31;

#define PROD_TOKEN(TOK, SEL, U, EV)                                          \
        {                                                                    \
            float za0 = bja, zb0 = bjb;                                      \
            float za1 = 0.f, za2 = 0.f, za3 = 0.f;                           \
            float zb1 = 0.f, zb2 = 0.f, zb3 = 0.f;                           \
            _Pragma("unroll")                                                \
            for (int k = 0; k < DD; k += 4) {                                \
                float e0 = readlane_f(EV, k);                                \
                float e1 = readlane_f(EV, k + 1);                            \
                float e2 = readlane_f(EV, k + 2);                            \
                float e3 = readlane_f(EV, k + 3);                            \
                za0 = fmaf(e0, ka[k], za0);     zb0 = fmaf(e0, kb[k], zb0);  \
                za1 = fmaf(e1, ka[k + 1], za1); zb1 = fmaf(e1, kb[k + 1], zb1); \
                za2 = fmaf(e2, ka[k + 2], za2); zb2 = fmaf(e2, kb[k + 2], zb2); \
                za3 = fmaf(e3, ka[k + 3], za3); zb3 = fmaf(e3, kb[k + 3], zb3); \
            }                                                                \
            ring[SEL][U][ja] = (za0 + za1) + (za2 + za3);                    \
            ring[SEL][U][jb] = (zb0 + zb1) + (zb2 + zb3);                    \
        }

        {
            int id0 = idsb[0]; if ((unsigned)id0 >= VOCABN) id0 = 0;
            float ec = emb[id0 * DD + dd];
#pragma unroll
            for (int u = 0; u < UU; ++u) {
                float en = 0.f;
                if (u + 1 < UU) {
                    int idn = idsb[u + 1]; if ((unsigned)idn >= VOCABN) idn = 0;
                    en = emb[idn * DD + dd];
                }
                PROD_TOKEN(u, 0, u, ec)
                ec = en;
            }
        }
        __syncthreads();
        int sel = 0;
        for (int t0 = 0; t0 < TT; t0 += UU) {
            if (t0 + UU < TT) {
                const int s = sel ^ 1;
                int id0 = idsb[t0 + UU]; if ((unsigned)id0 >= VOCABN) id0 = 0;
                float ec = emb[id0 * DD + dd];
#pragma unroll
                for (int u = 0; u < UU; ++u) {
                    float en = 0.f;
                    if (u + 1 < UU) {
                        int tn = t0 + UU + u + 1;
                        if (tn > TT - 1) tn = TT - 1;
                        int idn = idsb[tn]; if ((unsigned)idn >= VOCABN) idn = 0;
                        en = emb[idn * DD + dd];
                    }
                    PROD_TOKEN(t0 + UU + u, s, u, ec)
                    ec = en;
                }
            }
            __syncthreads();
            sel ^= 1;
        }
#undef PROD_TOKEN
        return;
    }

    // ---------------- consumer: R3-exact scan, xg from ring ----------------
    const int d = l & 31;
    const bool hi = l >= 32;
    const int ga = (hi ? 32 : 0) + d;
    const int gb = (hi ? 96 : 64) + d;
    float rka[DD], rkb[DD];
#pragma unroll
    for (int k = 0; k < DD; ++k) { rka[k] = rk[k * GG + ga]; rkb[k] = rk[k * GG + gb]; }
    float* hb = hout + (size_t)b * TT * DD;

    float h = 0.0f, c = 0.0f;
    __syncthreads();   // matches producer prologue barrier
    int sel = 0;
    for (int t0 = 0; t0 < TT; t0 += UU) {
        float pa[UU], pb[UU];
#pragma unroll
        for (int u = 0; u < UU; ++u) {
            pa[u] = ring[sel][u][ga];
            pb[u] = ring[sel][u][gb];
        }
#pragma unroll
        for (int u = 0; u < UU; ++u) {
            float za0 = pa[u], zb0 = pb[u];
            float za1 = 0.f, za2 = 0.f, za3 = 0.f;
            float zb1 = 0.f, zb2 = 0.f, zb3 = 0.f;
#pragma unroll
            for (int k = 0; k < DD; k += 4) {
                float h0 = readlane_f(h, k);
                float h1 = readlane_f(h, k + 1);
                float h2 = readlane_f(h, k + 2);
                float h3 = readlane_f(h, k + 3);
                za0 = fmaf(h0, rka[k], za0);     zb0 = fmaf(h0, rkb[k], zb0);
                za1 = fmaf(h1, rka[k + 1], za1); zb1 = fmaf(h1, rkb[k + 1], zb1);
                za2 = fmaf(h2, rka[k + 2], za2); zb2 = fmaf(h2, rkb[k + 2], zb2);
                za3 = fmaf(h3, rka[k + 3], za3); zb3 = fmaf(h3, rkb[k + 3], zb3);
            }
            float za = (za0 + za1) + (za2 + za3);
            float zb = (zb0 + zb1) + (zb2 + zb3);
            float a = fsig(za);                       // sig(i) lo / sig(f) hi
            float zbm = hi ? zb : 2.0f * zb;
            float s2 = fsig(zbm);
            float bv = hi ? s2 : 2.0f * s2 - 1.0f;    // sig(o) hi / tanh(g) lo
            float fg = __shfl_xor(a, 32);
            float og = __shfl_xor(bv, 32);
            c = fmaf(fg, c, a * bv);
            float tc = 2.0f * fsig(2.0f * c) - 1.0f;
            h = og * tc;
            if (!hi) hb[(t0 + u) * DD + d] = h;
        }
        __syncthreads();
        sel ^= 1;
    }
}

// ---------------------------------------------------------------------------
// Kernel 2: cvt — R13 version (XCD-swizzled, 256 blocks), unchanged.
// ---------------------------------------------------------------------------
__global__ __launch_bounds__(256) void k_cvt(const float* __restrict__ h,
                                             u16* __restrict__ hh, u16* __restrict__ hl,
                                             u16* __restrict__ th, u16* __restrict__ tl) {
    const int b = blockIdx.x & 63;
    const int seg = blockIdx.x >> 6;
    const int tid = threadIdx.x;
    const float* hsrc = h + (size_t)b * TT * DD;
    const size_t rb = (size_t)b * TT * DD;
    const size_t tb = (size_t)b * DD * TT;
    __shared__ float tile[64][33];
    for (int t0 = seg * 256; t0 < seg * 256 + 256; t0 += 64) {
#pragma unroll
        for (int n = 0; n < 2; ++n) {
            int idx = tid + n * 256;
            int row = idx >> 3, c4 = idx & 7;
            float4 v = *(const float4*)&hsrc[(size_t)(t0 + row) * DD + c4 * 4];
            float xs[4] = {v.x, v.y, v.z, v.w};
            u16 hi4[4], lo4[4];
#pragma unroll
            for (int i = 0; i < 4; ++i) {
                tile[row][c4 * 4 + i] = xs[i];
                hi4[i] = f2bf_rne(xs[i]);
                lo4[i] = f2bf_rne(xs[i] - bf2f(hi4[i]));
            }
            ushort4 hv = {hi4[0], hi4[1], hi4[2], hi4[3]};
            ushort4 lv = {lo4[0], lo4[1], lo4[2], lo4[3]};
            *(ushort4*)&hh[rb + (size_t)(t0 + row) * DD + c4 * 4] = hv;
            *(ushort4*)&hl[rb + (size_t)(t0 + row) * DD + c4 * 4] = lv;
        }
        __syncthreads();
#pragma unroll
        for (int n = 0; n < 8; ++n) {
            int flat = tid + n * 256;
            int dd = flat >> 6, tt = flat & 63;
            float x = tile[tt][dd];
            u16 hv = f2bf_rne(x);
            u16 lv = f2bf_rne(x - bf2f(hv));
            th[tb + (size_t)dd * TT + t0 + tt] = hv;
            tl[tb + (size_t)dd * TT + t0 + tt] = lv;
        }
        __syncthreads();
    }
}

// ---------------------------------------------------------------------------
// Kernel 3: attention on MFMA — R16 P-lag version (absmax 0.0, measured).
// XCD swizzle (b = blk&63 -> XCD b%8) + register K/V prefetch + P-lag
// software pipeline (PV of kp-1 during iteration kp).
// ---------------------------------------------------------------------------
__global__ __launch_bounds__(256, 4) void k_attn(const u16* __restrict__ hh,
                                                 const u16* __restrict__ hl,
                                                 const u16* __restrict__ th,
                                                 const u16* __restrict__ tl,
                                                 float* __restrict__ ctx) {
    __shared__ u16 plds[4][2][16 * 40];   // per-wave double-buffered P
    const int tid = threadIdx.x;
    const int w = tid >> 6;
    const int l = tid & 63;
    const int m = l & 15;
    const int g = l >> 4;
    const int b = blockIdx.x & 63;              // XCD swizzle: XCD = b % 8
    const int qt = (blockIdx.x >> 6) * 4 + w;
    const int q0 = qt * 16;
    const size_t rb = (size_t)b * TT * DD;
    const size_t tb = (size_t)b * DD * TT;

    const short8 Qh = *(const short8*)&hh[rb + (size_t)(q0 + m) * DD + g * 8];
    const short8 Ql = *(const short8*)&hl[rb + (size_t)(q0 + m) * DD + g * 8];
    short8 ONES;
#pragma unroll
    for (int j = 0; j < 8; ++j) ONES[j] = (short)0x3F80;

    floatx4 c0 = {0.f, 0.f, 0.f, 0.f};
    floatx4 c1 = {0.f, 0.f, 0.f, 0.f};
    floatx4 la = {0.f, 0.f, 0.f, 0.f};

#define S_BLOCK(KH_A, KL_A, KH_B, KL_B, SA, SB)                               \
    SA = __builtin_amdgcn_mfma_f32_16x16x32_bf16(Qh, KH_A, SA, 0, 0, 0);      \
    SA = __builtin_amdgcn_mfma_f32_16x16x32_bf16(Qh, KL_A, SA, 0, 0, 0);      \
    SA = __builtin_amdgcn_mfma_f32_16x16x32_bf16(Ql, KH_A, SA, 0, 0, 0);      \
    SB = __builtin_amdgcn_mfma_f32_16x16x32_bf16(Qh, KH_B, SB, 0, 0, 0);      \
    SB = __builtin_amdgcn_mfma_f32_16x16x32_bf16(Qh, KL_B, SB, 0, 0, 0);      \
    SB = __builtin_amdgcn_mfma_f32_16x16x32_bf16(Ql, KH_B, SB, 0, 0, 0);

    // ---- kp = 0: S + exp + write slot0; no PV yet ----
    {
        short8 KhA = *(const short8*)&hh[rb + (size_t)(m) * DD + g * 8];
        short8 KlA = *(const short8*)&hl[rb + (size_t)(m) * DD + g * 8];
        short8 KhB = *(const short8*)&hh[rb + (size_t)(16 + m) * DD + g * 8];
        short8 KlB = *(const short8*)&hl[rb + (size_t)(16 + m) * DD + g * 8];
        floatx4 sA = {0.f, 0.f, 0.f, 0.f};
        floatx4 sB = {0.f, 0.f, 0.f, 0.f};
        S_BLOCK(KhA, KlA, KhB, KlB, sA, sB)
        u16* lds0 = plds[w][0];
#pragma unroll
        for (int r = 0; r < 4; ++r) {
            lds0[(g * 4 + r) * 40 + m]      = f2bf_rne(__expf(sA[r]));
            lds0[(g * 4 + r) * 40 + 16 + m] = f2bf_rne(__expf(sB[r]));
        }
    }
    // preload V_0 (used at kp=1) and K_1
    short8 Vh0 = *(const short8*)&th[tb + (size_t)m * TT + g * 8];
    short8 Vl0 = *(const short8*)&tl[tb + (size_t)m * TT + g * 8];
    short8 Vh1 = *(const short8*)&th[tb + (size_t)(16 + m) * TT + g * 8];
    short8 Vl1 = *(const short8*)&tl[tb + (size_t)(16 + m) * TT + g * 8];
    short8 KhA = *(const short8*)&hh[rb + (size_t)(32 + m) * DD + g * 8];
    short8 KlA = *(const short8*)&hl[rb + (size_t)(32 + m) * DD + g * 8];
    short8 KhB = *(const short8*)&hh[rb + (size_t)(48 + m) * DD + g * 8];
    short8 KlB = *(const short8*)&hl[rb + (size_t)(48 + m) * DD + g * 8];

#pragma unroll 1
    for (int kp = 1; kp < 32; ++kp) {
        const int knK = (kp < 31) ? (kp + 1) * 32 : 0;
        const int knV = kp * 32;
        short8 nKhA = *(const short8*)&hh[rb + (size_t)(knK + m) * DD + g * 8];
        short8 nKlA = *(const short8*)&hl[rb + (size_t)(knK + m) * DD + g * 8];
        short8 nKhB = *(const short8*)&hh[rb + (size_t)(knK + 16 + m) * DD + g * 8];
        short8 nKlB = *(const short8*)&hl[rb + (size_t)(knK + 16 + m) * DD + g * 8];
        short8 nVh0 = *(const short8*)&th[tb + (size_t)m * TT + knV + g * 8];
        short8 nVl0 = *(const short8*)&tl[tb + (size_t)m * TT + knV + g * 8];
        short8 nVh1 = *(const short8*)&th[tb + (size_t)(16 + m) * TT + knV + g * 8];
        short8 nVl1 = *(const short8*)&tl[tb + (size_t)(16 + m) * TT + knV + g * 8];

        floatx4 sA = {0.f, 0.f, 0.f, 0.f};
        floatx4 sB = {0.f, 0.f, 0.f, 0.f};
        S_BLOCK(KhA, KlA, KhB, KlB, sA, sB)

        const short8 P = *(const short8*)&plds[w][(kp - 1) & 1][m * 40 + g * 8];

        u16 pe[8];
#pragma unroll
        for (int r = 0; r < 4; ++r) {
            pe[r]     = f2bf_rne(__expf(sA[r]));
            pe[4 + r] = f2bf_rne(__expf(sB[r]));
        }

        c0 = __builtin_amdgcn_mfma_f32_16x16x32_bf16(P, Vh0, c0, 0, 0, 0);
        c0 = __builtin_amdgcn_mfma_f32_16x16x32_bf16(P, Vl0, c0, 0, 0, 0);
        c1 = __builtin_amdgcn_mfma_f32_16x16x32_bf16(P, Vh1, c1, 0, 0, 0);
        c1 = __builtin_amdgcn_mfma_f32_16x16x32_bf16(P, Vl1, c1, 0, 0, 0);
        la = __builtin_amdgcn_mfma_f32_16x16x32_bf16(P, ONES, la, 0, 0, 0);

        u16* lds = plds[w][kp & 1];
#pragma unroll
        for (int r = 0; r < 4; ++r) {
            lds[(g * 4 + r) * 40 + m]      = pe[r];
            lds[(g * 4 + r) * 40 + 16 + m] = pe[4 + r];
        }

        KhA = nKhA; KlA = nKlA; KhB = nKhB; KlB = nKlB;
        Vh0 = nVh0; Vl0 = nVl0; Vh1 = nVh1; Vl1 = nVl1;
    }
    // epilogue: PV of kp=31
    {
        const short8 P = *(const short8*)&plds[w][31 & 1][m * 40 + g * 8];
        c0 = __builtin_amdgcn_mfma_f32_16x16x32_bf16(P, Vh0, c0, 0, 0, 0);
        c0 = __builtin_amdgcn_mfma_f32_16x16x32_bf16(P, Vl0, c0, 0, 0, 0);
        c1 = __builtin_amdgcn_mfma_f32_16x16x32_bf16(P, Vh1, c1, 0, 0, 0);
        c1 = __builtin_amdgcn_mfma_f32_16x16x32_bf16(P, Vl1, c1, 0, 0, 0);
        la = __builtin_amdgcn_mfma_f32_16x16x32_bf16(P, ONES, la, 0, 0, 0);
    }
#undef S_BLOCK
#pragma unroll
    for (int r = 0; r < 4; ++r) {
        float linv = __builtin_amdgcn_rcpf(la[r]);
        float* crow = ctx + (size_t)b * TT * DD + (size_t)(q0 + g * 4 + r) * DD;
        crow[m]      = c0[r] * linv;
        crow[16 + m] = c1[r] * linv;
    }
}

// ---------------------------------------------------------------------------
// Kernel 4: ymlp — R13 version, unchanged.
// ---------------------------------------------------------------------------
__global__ __launch_bounds__(256) void k_ymlp(const float* __restrict__ ctx,
                                              const float* __restrict__ h,
                                              const float* __restrict__ W1,
                                              const float* __restrict__ b1,
                                              const float* __restrict__ W2,
                                              const float* __restrict__ b2,
                                              float* __restrict__ out) {
    const int b = blockIdx.x;
    const int tid = threadIdx.x;
    __shared__ __align__(16) float cs[128 * DD];
    __shared__ __align__(16) float hs[128 * DD];
    const float* cb = ctx + (size_t)b * TT * DD;
    const float* hb = h + (size_t)b * TT * DD;
    const int e = tid & 31;
    const int d4 = (tid >> 5) * 4;
    float acc[4] = {0.f, 0.f, 0.f, 0.f};
    for (int kt = 0; kt < 8; ++kt) {
        const float4* s1 = (const float4*)(cb + (size_t)kt * 128 * DD);
        const float4* s2 = (const float4*)(hb + (size_t)kt * 128 * DD);
        float4* t1 = (float4*)cs;
        float4* t2 = (float4*)hs;
#pragma unroll
        for (int n = 0; n < 4; ++n) {
            t1[tid + n * 256] = s1[tid + n * 256];
            t2[tid + n * 256] = s2[tid + n * 256];
        }
        __syncthreads();
#pragma unroll 2
        for (int s = 0; s < 128; ++s) {
            float hv = hs[s * DD + e];
            float4 cv = *(const float4*)&cs[s * DD + d4];
            acc[0] = fmaf(cv.x, hv, acc[0]);
            acc[1] = fmaf(cv.y, hv, acc[1]);
            acc[2] = fmaf(cv.z, hv, acc[2]);
            acc[3] = fmaf(cv.w, hv, acc[3]);
        }
        __syncthreads();
    }
    __shared__ float ys[DD][DD];
#pragma unroll
    for (int r = 0; r < 4; ++r) ys[d4 + r][e] = acc[r];
    __syncthreads();
    __shared__ float yr[DD][33];
#pragma unroll
    for (int r = 0; r < 4; ++r) {
        float v = b1[e];
#pragma unroll
        for (int ee = 0; ee < DD; ++ee) v += ys[d4 + r][ee] * W1[ee * DD + e];
        yr[d4 + r][e] = fmaxf(v, 0.0f);
    }
    __syncthreads();
    if (tid < DD) {
        float v = b2[0];
#pragma unroll
        for (int ee = 0; ee < DD; ++ee) v += yr[tid][ee] * W2[ee];
        out[b * DD + tid] = 1.0f / (1.0f + expf(-v));
    }
}

// ---------------------------------------------------------------------------
extern "C" void kernel_launch(void* const* d_in, const int* in_sizes, int n_in,
                              void* d_out, int out_size, void* d_ws, size_t ws_size,
                              hipStream_t stream) {
    const int* ids   = (const int*)d_in[0];
    const float* emb = (const float*)d_in[1];
    const float* kl  = (const float*)d_in[2];
    const float* rk  = (const float*)d_in[3];
    const float* bl  = (const float*)d_in[4];
    const float* W1  = (const float*)d_in[5];
    const float* b1  = (const float*)d_in[6];
    const float* W2  = (const float*)d_in[7];
    const float* b2  = (const float*)d_in[8];
    float* out = (float*)d_out;

    char* ws = (char*)d_ws;
    const size_t H_ELEMS = (size_t)BB * TT * DD;   // 2,097,152
    u16* hh   = (u16*)ws;
    u16* hl   = (u16*)(ws + H_ELEMS * 2);
    u16* th   = (u16*)(ws + H_ELEMS * 4);
    u16* tl   = (u16*)(ws + H_ELEMS * 6);
    float* h  = (float*)(ws + H_ELEMS * 8);
    float* ctx = (float*)(ws + H_ELEMS * 8 + H_ELEMS * 4);
    int* list = (int*)(ws + H_ELEMS * 8 + H_ELEMS * 8);

    k_lstm_scan<<<BB + 1, 128, 0, stream>>>(ids, emb, kl, bl, rk, h, list, out + BB * DD);
    k_cvt<<<256, 256, 0, stream>>>(h, hh, hl, th, tl);
    k_attn<<<BB * 16, 256, 0, stream>>>(hh, hl, th, tl, ctx);
    k_ymlp<<<BB, 256, 0, stream>>>(ctx, h, W1, b1, W2, b2, out);
}